// Round 1
// baseline (1100.358 us; speedup 1.0000x reference)
//
#include <hip/hip_runtime.h>
#include <cstdint>

// ---------------------------------------------------------------------------
// CVTransformer: L=4, D=256, H=8, DH=32, WS=128, FF=1024, B=2, N=8192
// Strategy: fp32 residual stream X[16384][512] (real|imag cols).
// All matmuls as bf16 MFMA GEMMs with K = 2*D (real|imag stacked along K).
// Weights repacked (transposed [N][K], bf16) each call.
// ---------------------------------------------------------------------------

typedef __bf16 bf16x8 __attribute__((ext_vector_type(8)));
typedef float  f32x4  __attribute__((ext_vector_type(4)));

#define M_TOK 16384
#define LDX   512

__device__ __forceinline__ unsigned short f2bf(float f) {
    union { float f; unsigned int u; } v; v.f = f;
    unsigned int r = v.u + 0x7FFFu + ((v.u >> 16) & 1u);
    return (unsigned short)(r >> 16);
}

__device__ __forceinline__ void async16(const void* g, void* l) {
    __builtin_amdgcn_global_load_lds(
        (const __attribute__((address_space(1))) void*)g,
        (__attribute__((address_space(3))) void*)l, 16, 0, 0);
}

// ----------------------------- elementwise ---------------------------------

__global__ __launch_bounds__(256) void copyin_kernel(const float* __restrict__ xr,
                                                     const float* __restrict__ xi,
                                                     float* __restrict__ X) {
    int idx = blockIdx.x * 256 + threadIdx.x;       // float4 over [16384][128]
    int t = idx >> 7, c4 = idx & 127;
    float4 v = (c4 < 64) ? ((const float4*)xr)[t * 64 + c4]
                         : ((const float4*)xi)[t * 64 + (c4 - 64)];
    ((float4*)X)[idx] = v;
}

__global__ __launch_bounds__(256) void unpack_kernel(const float* __restrict__ X,
                                                     float* __restrict__ out) {
    int idx = blockIdx.x * 256 + threadIdx.x;       // float4 over [2][16384][64]
    int p = idx >> 20;                               // 1048576 f4 per plane
    int rem = idx & 1048575;
    int t = rem >> 6, d4 = rem & 63;
    ((float4*)out)[idx] = ((const float4*)X)[t * 128 + p * 64 + d4];
}

// ----------------------------- weight packing ------------------------------
// Packed layout: Bt[n][k], k = 0..2D-1 (real then imag input planes).

__global__ __launch_bounds__(256) void pack_qkv_kernel(
    const float* __restrict__ Wq_r, const float* __restrict__ Wq_i,
    const float* __restrict__ Wk_r, const float* __restrict__ Wk_i,
    const float* __restrict__ Wv_r, const float* __restrict__ Wv_i,
    unsigned short* __restrict__ out) {
    int idx = blockIdx.x * 256 + threadIdx.x;       // L*1536*512
    int l = idx / 786432;
    int rem = idx - l * 786432;
    int n = rem >> 9, k = rem & 511;
    int blk = n >> 8;                                // 0..5 : qr qi kr ki vr vi
    int no = n & 255, kk = k & 255;
    bool khi = (k >= 256);
    bool imag = (blk & 1);
    const float *Wr, *Wi;
    int proj = blk >> 1;
    if (proj == 0)      { Wr = Wq_r; Wi = Wq_i; }
    else if (proj == 1) { Wr = Wk_r; Wi = Wk_i; }
    else                { Wr = Wv_r; Wi = Wv_i; }
    int wi = l * 65536 + kk * 256 + no;
    float val = !imag ? (khi ? -Wi[wi] : Wr[wi])
                      : (khi ?  Wr[wi] : Wi[wi]);
    out[idx] = f2bf(val);
}

__global__ __launch_bounds__(256) void pack_o_kernel(
    const float* __restrict__ Wo_r, const float* __restrict__ Wo_i,
    unsigned short* __restrict__ out) {
    int idx = blockIdx.x * 256 + threadIdx.x;       // L*512*512
    int l = idx >> 18;
    int rem = idx & 262143;
    int n = rem >> 9, k = rem & 511;
    bool imag = (n >= 256);
    int no = n & 255, kk = k & 255;
    bool khi = (k >= 256);
    int wi = l * 65536 + kk * 256 + no;
    float val = !imag ? (khi ? -Wo_i[wi] : Wo_r[wi])
                      : (khi ?  Wo_r[wi] : Wo_i[wi]);
    out[idx] = f2bf(val);
}

__global__ __launch_bounds__(256) void pack_ffn1_kernel(
    const float* __restrict__ W1_r, const float* __restrict__ W1_i,
    unsigned short* __restrict__ out) {
    int idx = blockIdx.x * 256 + threadIdx.x;       // L*2048*512
    int l = idx >> 20;
    int rem = idx & 1048575;
    int n = rem >> 9, k = rem & 511;
    bool imag = (n >= 1024);
    int no = imag ? n - 1024 : n;
    int kk = k & 255;
    bool khi = (k >= 256);
    int wi = l * 262144 + kk * 1024 + no;
    float val = !imag ? (khi ? -W1_i[wi] : W1_r[wi])
                      : (khi ?  W1_r[wi] : W1_i[wi]);
    out[idx] = f2bf(val);
}

__global__ __launch_bounds__(256) void pack_ffn2_kernel(
    const float* __restrict__ W2_r, const float* __restrict__ W2_i,
    unsigned short* __restrict__ out) {
    int idx = blockIdx.x * 256 + threadIdx.x;       // L*512*2048
    int l = idx >> 20;
    int rem = idx & 1048575;
    int n = rem >> 11, k = rem & 2047;
    bool imag = (n >= 256);
    int no = n & 255;
    int kk = k & 1023;
    bool khi = (k >= 1024);
    int wi = l * 262144 + kk * 256 + no;
    float val = !imag ? (khi ? -W2_i[wi] : W2_r[wi])
                      : (khi ?  W2_r[wi] : W2_i[wi]);
    out[idx] = f2bf(val);
}

__global__ __launch_bounds__(256) void pack_bias_kernel(
    const float* __restrict__ b1r, const float* __restrict__ b1i,
    const float* __restrict__ b2r, const float* __restrict__ b2i,
    float* __restrict__ B1, float* __restrict__ B2) {
    int idx = blockIdx.x * 256 + threadIdx.x;       // 4*2048 + 4*512 = 10240
    if (idx < 8192) {
        int l = idx >> 11, n = idx & 2047;
        bool imag = (n >= 1024);
        int no = imag ? n - 1024 : n;
        int bi = l * 1024 + no;
        B1[idx] = imag ? (b1r[bi] + b1i[bi]) : (b1r[bi] - b1i[bi]);
    } else {
        int i2 = idx - 8192;
        int l = i2 >> 9, n = i2 & 511;
        bool imag = (n >= 256);
        int no = n & 255;
        int bi = l * 256 + no;
        B2[i2] = imag ? (b2r[bi] + b2i[bi]) : (b2r[bi] - b2i[bi]);
    }
}

// ----------------------------- rmsnorm -------------------------------------

__global__ __launch_bounds__(256) void rmsnorm_kernel(const float* __restrict__ X,
                                                      const float* __restrict__ scale,
                                                      unsigned short* __restrict__ out) {
    int row = blockIdx.x * 4 + (threadIdx.x >> 6);
    int lane = threadIdx.x & 63;
    const float4* xrow = (const float4*)(X + (size_t)row * LDX);
    float4 xr = xrow[lane];
    float4 xi = xrow[64 + lane];
    float ss = xr.x * xr.x + xr.y * xr.y + xr.z * xr.z + xr.w * xr.w
             + xi.x * xi.x + xi.y * xi.y + xi.z * xi.z + xi.w * xi.w;
#pragma unroll
    for (int m = 1; m < 64; m <<= 1) ss += __shfl_xor(ss, m);
    float inv = 1.0f / sqrtf(ss * (1.0f / 256.0f) + 1e-8f);
    float4 sc = ((const float4*)scale)[lane];
    ushort4 o0, o1;
    o0.x = f2bf(xr.x * inv * sc.x); o0.y = f2bf(xr.y * inv * sc.y);
    o0.z = f2bf(xr.z * inv * sc.z); o0.w = f2bf(xr.w * inv * sc.w);
    o1.x = f2bf(xi.x * inv * sc.x); o1.y = f2bf(xi.y * inv * sc.y);
    o1.z = f2bf(xi.z * inv * sc.z); o1.w = f2bf(xi.w * inv * sc.w);
    ushort4* orow = (ushort4*)(out + (size_t)row * LDX);
    orow[lane] = o0;
    orow[64 + lane] = o1;
}

// ----------------------------- GEMM ----------------------------------------
// C[M,N] = A[M,K](bf16) @ Bt[N,K]^T(bf16).  128x128 tile, BK=64, 4 waves.
// MODE 0: write bf16.  MODE 1: +bias, exact GELU, write bf16.
// MODE 2: +bias(optional), accumulate fp32 into Xres (ld 512).

template <int MODE>
__global__ __launch_bounds__(256) void gemm_kernel(
    const unsigned short* __restrict__ A, const unsigned short* __restrict__ Bt,
    unsigned short* __restrict__ Obf, const float* __restrict__ bias,
    float* __restrict__ Xres, int K, int N) {
    __shared__ __align__(16) char smem[32768];
    char* sA = smem;
    char* sB = smem + 16384;
    const int tid = threadIdx.x;
    const int lane = tid & 63;
    const int wave = tid >> 6;
    const int g = lane >> 4;
    const int rl = lane & 15;
    const int wm = wave >> 1, wn = wave & 1;
    const int tM = blockIdx.y, tN = blockIdx.x;

    f32x4 acc[4][4];
#pragma unroll
    for (int i = 0; i < 4; ++i)
#pragma unroll
        for (int j = 0; j < 4; ++j)
#pragma unroll
            for (int v = 0; v < 4; ++v) acc[i][j][v] = 0.0f;

    const unsigned short* Abase = A + (size_t)tM * 128 * K;
    const unsigned short* Bbase = Bt + (size_t)tN * 128 * K;

    for (int kt = 0; kt < K; kt += 64) {
        // stage A,B tiles (128x64 bf16 each) via global_load_lds, XOR-swizzled
#pragma unroll
        for (int it = 0; it < 4; ++it) {
            int s = it * 256 + tid;
            int r = s >> 3;
            int c = (s & 7) ^ (r & 7);
            async16(Abase + (size_t)r * K + kt + c * 8, sA + (it * 256 + wave * 64) * 16);
            async16(Bbase + (size_t)r * K + kt + c * 8, sB + (it * 256 + wave * 64) * 16);
        }
        asm volatile("s_waitcnt vmcnt(0)" ::: "memory");
        __syncthreads();
#pragma unroll
        for (int ks = 0; ks < 2; ++ks) {
            bf16x8 aF[4], bF[4];
#pragma unroll
            for (int fm = 0; fm < 4; ++fm) {
                int r = wm * 64 + fm * 16 + rl;
                int c = ks * 4 + g;
                aF[fm] = *(const bf16x8*)(sA + r * 128 + ((c ^ (r & 7)) << 4));
            }
#pragma unroll
            for (int fn = 0; fn < 4; ++fn) {
                int r = wn * 64 + fn * 16 + rl;
                int c = ks * 4 + g;
                bF[fn] = *(const bf16x8*)(sB + r * 128 + ((c ^ (r & 7)) << 4));
            }
#pragma unroll
            for (int fm = 0; fm < 4; ++fm)
#pragma unroll
                for (int fn = 0; fn < 4; ++fn)
                    acc[fm][fn] = __builtin_amdgcn_mfma_f32_16x16x32_bf16(
                        aF[fm], bF[fn], acc[fm][fn], 0, 0, 0);
        }
        __syncthreads();
    }

#pragma unroll
    for (int fm = 0; fm < 4; ++fm)
#pragma unroll
        for (int fn = 0; fn < 4; ++fn)
#pragma unroll
            for (int v = 0; v < 4; ++v) {
                int row = tM * 128 + wm * 64 + fm * 16 + g * 4 + v;
                int col = tN * 128 + wn * 64 + fn * 16 + rl;
                float val = acc[fm][fn][v];
                if (MODE == 0) {
                    Obf[(size_t)row * N + col] = f2bf(val);
                } else if (MODE == 1) {
                    float x = val + bias[col];
                    float ge = 0.5f * x * (1.0f + erff(x * 0.70710678118654752f));
                    Obf[(size_t)row * N + col] = f2bf(ge);
                } else {
                    float x = val + (bias ? bias[col] : 0.0f);
                    Xres[(size_t)row * LDX + col] += x;
                }
            }
}

// ----------------------------- windowed attention --------------------------
// One block per (window, head, batch).  QKV buffer: [16384][1536] bf16,
// cols: qr qi kr ki vr vi (256 each).  Output: [16384][512] bf16 (or|oi).

#define AT_KOFF 16384
#define AT_VOFF 34816
#define AT_ROFF 52224

__global__ __launch_bounds__(256) void attn_kernel(
    const unsigned short* __restrict__ qkv, const float* __restrict__ relb_g,
    unsigned short* __restrict__ attout) {
    __shared__ __align__(16) char smem[53264];
    const int tid = threadIdx.x;
    const int lane = tid & 63;
    const int wq = tid >> 6;
    const int g = lane >> 4;
    const int rl = lane & 15;
    const int w = blockIdx.x, h = blockIdx.y, b = blockIdx.z;
    const int tok0 = b * 8192 + w * 128;
    float* relb = (float*)(smem + AT_ROFF);

    for (int i = tid; i < 257; i += 256) relb[i] = relb_g[i];

    // stage Qc,Kc [128][64] bf16 (real|imag along K), XOR chunk swizzle
#pragma unroll
    for (int it = 0; it < 4; ++it) {
        int s = it * 256 + tid;
        int r = s >> 3;
        int c = (s & 7) ^ (r & 7);
        int colq = (c < 4) ? (h * 32 + c * 8) : (256 + h * 32 + (c - 4) * 8);
        const unsigned short* rowp = qkv + (size_t)(tok0 + r) * 1536;
        *(float4*)(smem + s * 16) = *(const float4*)(rowp + colq);
        *(float4*)(smem + AT_KOFF + s * 16) = *(const float4*)(rowp + colq + 512);
    }
    // stage Vt [64][136] bf16: Vt[d'][j] ; d' 0..31 = vr, 32..63 = vi
#pragma unroll
    for (int it = 0; it < 4; ++it) {
        int e = it * 256 + tid;
        int j = e >> 3;
        int d0 = (e & 7) * 8;
        int colv = (d0 < 32) ? (1024 + h * 32 + d0) : (1280 + h * 32 + (d0 - 32));
        float4 vv = *(const float4*)(qkv + (size_t)(tok0 + j) * 1536 + colv);
        const unsigned short* u = (const unsigned short*)&vv;
#pragma unroll
        for (int k = 0; k < 8; ++k)
            *(unsigned short*)(smem + AT_VOFF + ((d0 + k) * 136 + j) * 2) = u[k];
    }
    __syncthreads();

    // S = Qc @ Kc^T  (covers qr.kr + qi.ki via K=64)
    f32x4 accS[2][8];
#pragma unroll
    for (int i = 0; i < 2; ++i)
#pragma unroll
        for (int j = 0; j < 8; ++j)
#pragma unroll
            for (int v = 0; v < 4; ++v) accS[i][j][v] = 0.0f;

#pragma unroll
    for (int ks = 0; ks < 2; ++ks) {
        bf16x8 qf[2], kf[8];
        int c = ks * 4 + g;
#pragma unroll
        for (int fm = 0; fm < 2; ++fm) {
            int r = wq * 32 + fm * 16 + rl;
            qf[fm] = *(const bf16x8*)(smem + r * 128 + ((c ^ (r & 7)) << 4));
        }
#pragma unroll
        for (int fn = 0; fn < 8; ++fn) {
            int r = fn * 16 + rl;
            kf[fn] = *(const bf16x8*)(smem + AT_KOFF + r * 128 + ((c ^ (r & 7)) << 4));
        }
#pragma unroll
        for (int fm = 0; fm < 2; ++fm)
#pragma unroll
            for (int fn = 0; fn < 8; ++fn)
                accS[fm][fn] = __builtin_amdgcn_mfma_f32_16x16x32_bf16(
                    qf[fm], kf[fn], accS[fm][fn], 0, 0, 0);
    }

    // softmax (rows live in 16-lane groups)
#pragma unroll
    for (int fm = 0; fm < 2; ++fm)
#pragma unroll
        for (int v = 0; v < 4; ++v) {
            int i = wq * 32 + fm * 16 + g * 4 + v;
            float m = -1e30f;
#pragma unroll
            for (int fn = 0; fn < 8; ++fn) {
                int j = fn * 16 + rl;
                float s = accS[fm][fn][v] * 0.17677669529663687f + relb[j - i + 128];
                accS[fm][fn][v] = s;
                m = fmaxf(m, s);
            }
            m = fmaxf(m, __shfl_xor(m, 1));
            m = fmaxf(m, __shfl_xor(m, 2));
            m = fmaxf(m, __shfl_xor(m, 4));
            m = fmaxf(m, __shfl_xor(m, 8));
            float sum = 0.0f;
#pragma unroll
            for (int fn = 0; fn < 8; ++fn) {
                float p = __expf(accS[fm][fn][v] - m);
                accS[fm][fn][v] = p;
                sum += p;
            }
            sum += __shfl_xor(sum, 1);
            sum += __shfl_xor(sum, 2);
            sum += __shfl_xor(sum, 4);
            sum += __shfl_xor(sum, 8);
            float inv = 1.0f / sum;
#pragma unroll
            for (int fn = 0; fn < 8; ++fn) accS[fm][fn][v] *= inv;
        }

    __syncthreads();   // all Qc/Kc reads done before P overwrites them

    // write P [128][136] bf16 at offset 0
#pragma unroll
    for (int fm = 0; fm < 2; ++fm)
#pragma unroll
        for (int fn = 0; fn < 8; ++fn)
#pragma unroll
            for (int v = 0; v < 4; ++v) {
                int i = wq * 32 + fm * 16 + g * 4 + v;
                int j = fn * 16 + rl;
                ((unsigned short*)smem)[i * 136 + j] = f2bf(accS[fm][fn][v]);
            }
    __syncthreads();

    // O = P @ V   (combined cols: 0..31 = or, 32..63 = oi)
    f32x4 accO[2][4];
#pragma unroll
    for (int i = 0; i < 2; ++i)
#pragma unroll
        for (int j = 0; j < 4; ++j)
#pragma unroll
            for (int v = 0; v < 4; ++v) accO[i][j][v] = 0.0f;

#pragma unroll
    for (int ks = 0; ks < 4; ++ks) {
        bf16x8 pf[2], vf[4];
#pragma unroll
        for (int fm = 0; fm < 2; ++fm) {
            int r = wq * 32 + fm * 16 + rl;
            pf[fm] = *(const bf16x8*)(smem + r * 272 + ks * 64 + g * 16);
        }
#pragma unroll
        for (int fn = 0; fn < 4; ++fn) {
            int n = fn * 16 + rl;
            vf[fn] = *(const bf16x8*)(smem + AT_VOFF + n * 272 + ks * 64 + g * 16);
        }
#pragma unroll
        for (int fm = 0; fm < 2; ++fm)
#pragma unroll
            for (int fn = 0; fn < 4; ++fn)
                accO[fm][fn] = __builtin_amdgcn_mfma_f32_16x16x32_bf16(
                    pf[fm], vf[fn], accO[fm][fn], 0, 0, 0);
    }

#pragma unroll
    for (int fm = 0; fm < 2; ++fm)
#pragma unroll
        for (int fn = 0; fn < 4; ++fn)
#pragma unroll
            for (int v = 0; v < 4; ++v) {
                int i = wq * 32 + fm * 16 + g * 4 + v;
                int dc = fn * 16 + rl;
                int col = (dc < 32) ? (h * 32 + dc) : (256 + h * 32 + (dc - 32));
                attout[(size_t)(tok0 + i) * 512 + col] = f2bf(accO[fm][fn][v]);
            }
}

// ----------------------------- launch --------------------------------------

extern "C" void kernel_launch(void* const* d_in, const int* in_sizes, int n_in,
                              void* d_out, int out_size, void* d_ws, size_t ws_size,
                              hipStream_t stream) {
    const float* x_real = (const float*)d_in[0];
    const float* x_imag = (const float*)d_in[1];
    const float* Wq_r = (const float*)d_in[2];
    const float* Wq_i = (const float*)d_in[3];
    const float* Wk_r = (const float*)d_in[4];
    const float* Wk_i = (const float*)d_in[5];
    const float* Wv_r = (const float*)d_in[6];
    const float* Wv_i = (const float*)d_in[7];
    const float* Wo_r = (const float*)d_in[8];
    const float* Wo_i = (const float*)d_in[9];
    const float* rel_bias = (const float*)d_in[10];
    const float* norm1 = (const float*)d_in[11];
    const float* norm2 = (const float*)d_in[12];
    const float* W1_r = (const float*)d_in[13];
    const float* b1_r = (const float*)d_in[14];
    const float* W1_i = (const float*)d_in[15];
    const float* b1_i = (const float*)d_in[16];
    const float* W2_r = (const float*)d_in[17];
    const float* b2_r = (const float*)d_in[18];
    const float* W2_i = (const float*)d_in[19];
    const float* b2_i = (const float*)d_in[20];

    char* ws = (char*)d_ws;
    float*          X    = (float*)(ws + 0);                    // 32 MB
    unsigned short* NRM  = (unsigned short*)(ws + 33554432);    // 16 MB
    unsigned short* QKVH = (unsigned short*)(ws + 50331648);    // 64 MB (QKV / FFN-H)
    unsigned short* ATTO = (unsigned short*)(ws + 117440512);   // 16 MB
    unsigned short* WQKV = (unsigned short*)(ws + 134217728);   // 6 MB
    unsigned short* WO   = (unsigned short*)(ws + 140509184);   // 2 MB
    unsigned short* W1P  = (unsigned short*)(ws + 142606336);   // 8 MB
    unsigned short* W2P  = (unsigned short*)(ws + 150994944);   // 8 MB
    float*          B1   = (float*)(ws + 159383552);
    float*          B2   = (float*)(ws + 159416320);

    copyin_kernel<<<8192, 256, 0, stream>>>(x_real, x_imag, X);
    pack_qkv_kernel<<<12288, 256, 0, stream>>>(Wq_r, Wq_i, Wk_r, Wk_i, Wv_r, Wv_i, WQKV);
    pack_o_kernel<<<4096, 256, 0, stream>>>(Wo_r, Wo_i, WO);
    pack_ffn1_kernel<<<16384, 256, 0, stream>>>(W1_r, W1_i, W1P);
    pack_ffn2_kernel<<<16384, 256, 0, stream>>>(W2_r, W2_i, W2P);
    pack_bias_kernel<<<40, 256, 0, stream>>>(b1_r, b1_i, b2_r, b2_i, B1, B2);

    for (int l = 0; l < 4; ++l) {
        rmsnorm_kernel<<<4096, 256, 0, stream>>>(X, norm1 + l * 256, NRM);
        gemm_kernel<0><<<dim3(12, 128), 256, 0, stream>>>(
            NRM, WQKV + (size_t)l * 786432, QKVH, nullptr, nullptr, 512, 1536);
        attn_kernel<<<dim3(64, 8, 2), 256, 0, stream>>>(QKVH, rel_bias + l * 257, ATTO);
        gemm_kernel<2><<<dim3(4, 128), 256, 0, stream>>>(
            ATTO, WO + (size_t)l * 262144, nullptr, nullptr, X, 512, 512);
        rmsnorm_kernel<<<4096, 256, 0, stream>>>(X, norm2 + l * 256, NRM);
        gemm_kernel<1><<<dim3(16, 128), 256, 0, stream>>>(
            NRM, W1P + (size_t)l * 1048576, QKVH, B1 + l * 2048, nullptr, 512, 2048);
        gemm_kernel<2><<<dim3(4, 128), 256, 0, stream>>>(
            QKVH, W2P + (size_t)l * 1048576, nullptr, B2 + l * 512, X, 2048, 512);
    }
    unpack_kernel<<<8192, 256, 0, stream>>>(X, (float*)d_out);
}